// Round 1
// baseline (690.923 us; speedup 1.0000x reference)
//
#include <hip/hip_runtime.h>

typedef _Float16 f16x8 __attribute__((ext_vector_type(8)));
typedef float f32x4 __attribute__((ext_vector_type(4)));

#define SLOT_DW 2052            // dwords per (b,t) slot in ws (2050 used by spec, 2048 by frame)
#define NROWS 16384             // B*T
#define WT_BYTE_OFF 134479872   // 16384*2052*4 ; Wt (f16) lives after the slots

// ---------------- K0: transpose + scale W -> Wt[n][o][d] (f16, x4096) ----------------
__global__ __launch_bounds__(256) void k_transpose(const float* __restrict__ W,
                                                   _Float16* __restrict__ Wt) {
  int n = blockIdx.x;
  __shared__ _Float16 L[128 * 130];
  int tid = threadIdx.x;
  const float* Wn = W + (size_t)n * 16384;
  for (int el = tid; el < 16384; el += 256) {
    int d = el >> 7, o = el & 127;
    L[d * 130 + o] = (_Float16)(Wn[el] * 4096.0f);
  }
  __syncthreads();
  _Float16* Wtn = Wt + (size_t)n * 16384;
  for (int el = tid; el < 16384; el += 256) {
    int o = el >> 7, d = el & 127;
    Wtn[el] = L[d * 130 + o];
  }
}

// ---------------- KA: per-band GEMM, band[r][n*128+o] = sum_d z[r][n][d]*W[n][d][o] ----------------
// 64 rows x 128 cols per block, K=128, f16 MFMA 16x16x32. Output f16 (unscaled dot, no bias).
__global__ __launch_bounds__(256) void kA(const float* __restrict__ z,
                                          const _Float16* __restrict__ Wt,
                                          _Float16* __restrict__ band) {
  int mt = blockIdx.x;   // 0..255
  int n  = blockIdx.y;   // 0..21
  int r0 = mt * 64;
  __shared__ __align__(16) _Float16 As[64 * 136];
  __shared__ __align__(16) _Float16 Bs[128 * 136];
  int tid = threadIdx.x;
  int cg = tid & 15, rg = tid >> 4;

  // stage A: z rows -> f16 LDS
#pragma unroll
  for (int pass = 0; pass < 4; pass++) {
    int row = pass * 16 + rg;
    const float* src = z + ((size_t)(r0 + row) * 22 + n) * 128 + cg * 8;
    float4 v0 = *(const float4*)src;
    float4 v1 = *(const float4*)(src + 4);
    f16x8 h;
    h[0] = (_Float16)v0.x; h[1] = (_Float16)v0.y; h[2] = (_Float16)v0.z; h[3] = (_Float16)v0.w;
    h[4] = (_Float16)v1.x; h[5] = (_Float16)v1.y; h[6] = (_Float16)v1.z; h[7] = (_Float16)v1.w;
    *(f16x8*)&As[row * 136 + cg * 8] = h;
  }
  // stage B: Wt[n][o][d] tiles (already f16, transposed)
  const _Float16* Wn = Wt + (size_t)n * 16384;
#pragma unroll
  for (int pass = 0; pass < 8; pass++) {
    int o = pass * 16 + rg;
    *(f16x8*)&Bs[o * 136 + cg * 8] = *(const f16x8*)(Wn + o * 128 + cg * 8);
  }
  __syncthreads();

  int lane = tid & 63, wave = tid >> 6;
  int l16 = lane & 15, quad = lane >> 4;
  f32x4 acc[8];
#pragma unroll
  for (int nt = 0; nt < 8; nt++) acc[nt] = (f32x4){0.f, 0.f, 0.f, 0.f};
#pragma unroll
  for (int kb = 0; kb < 4; kb++) {
    f16x8 a = *(const f16x8*)&As[(wave * 16 + l16) * 136 + kb * 32 + quad * 8];
#pragma unroll
    for (int nt = 0; nt < 8; nt++) {
      f16x8 bf = *(const f16x8*)&Bs[(nt * 16 + l16) * 136 + kb * 32 + quad * 8];
      acc[nt] = __builtin_amdgcn_mfma_f32_16x16x32_f16(a, bf, acc[nt], 0, 0, 0);
    }
  }
  const float inv_scale = 1.0f / 4096.0f;  // undo W prescale
#pragma unroll
  for (int nt = 0; nt < 8; nt++) {
#pragma unroll
    for (int reg = 0; reg < 4; reg++) {
      int row = wave * 16 + quad * 4 + reg;
      band[(size_t)(r0 + row) * (SLOT_DW * 2) + n * 128 + nt * 16 + l16] =
          (_Float16)(acc[nt][reg] * inv_scale);
    }
  }
}

// ---------------- KB: gather mask, complex-mul mix, irfft(2048), window, write frame in-place ----------------
__global__ __launch_bounds__(256) void kB(const float* __restrict__ mix,
                                          const float* __restrict__ bias,
                                          float* __restrict__ ws) {
  int r = blockIdx.x;           // 0..16383
  int b = r >> 11, t = r & 2047;
  __shared__ unsigned band_u[1408];          // 2816 f16
  __shared__ float bias_l[2816];
  __shared__ float2 T[1025];                 // (cos,sin)(pi*k/1024)
  __shared__ float sr[1025], si[1025];
  __shared__ float2 bufA[1024], bufB[1024];
  int tid = threadIdx.x;

  const unsigned* slot_u = (const unsigned*)ws + (size_t)r * SLOT_DW;
  for (int i = tid; i < 1408; i += 256) band_u[i] = slot_u[i];
  for (int i = tid; i < 2816; i += 256) bias_l[i] = bias[i];
  for (int k = tid; k < 1025; k += 256) {
    float sv, cv;
    sincosf((float)k * 3.0679615757712823e-3f, &sv, &cv);  // pi/1024
    T[k] = make_float2(cv, sv);
  }
  __syncthreads();

  const _Float16* bh = (const _Float16*)band_u;
  const float* mixr = mix + ((size_t)(b * 2) * 2048 + t) * 1025;
  const float* mixi = mix + ((size_t)(b * 2 + 1) * 2048 + t) * 1025;
  for (int f = tid; f < 1025; f += 256) {
    float mr = 0.f, mi = 0.f;
    int wgt = 0;
#pragma unroll
    for (int n = 0; n < 22; n++) {
      int s = (n == 21) ? 961 : n * 48;
      unsigned u = (unsigned)(f - s);
      if (u < 64u) {
        int idx = n * 128 + 2 * (int)u;
        mr += (float)bh[idx]     + bias_l[idx];
        mi += (float)bh[idx + 1] + bias_l[idx + 1];
        wgt++;
      }
    }
    float inv = 1.0f / (float)wgt;   // wgt >= 1 for all f
    mr *= inv; mi *= inv;
    float xr = mixr[f], xi = mixi[f];
    float outr = mr * xr - mi * xi;
    float outi = mr * xi + mi * xr;
    if (f == 0 || f == 1024) outi = 0.0f;  // c2r ignores Im at DC/Nyquist
    sr[f] = outr; si[f] = outi;
  }
  __syncthreads();

  // pack real-IFFT(2048) into complex IFFT(1024): G[k] = (X[k]+conj(X[1024-k])) + i*e^{+i pi k/1024}*(X[k]-conj(X[1024-k]))
  for (int k = tid; k < 1024; k += 256) {
    float Xr = sr[k], Xi = si[k];
    float Yr = sr[1024 - k], Yi = -si[1024 - k];
    float Ar = Xr + Yr, Ai = Xi + Yi;
    float Br = Xr - Yr, Bi = Xi - Yi;
    float2 w = T[k];
    bufA[k] = make_float2(Ar - (w.x * Bi + w.y * Br), Ai + (w.x * Br - w.y * Bi));
  }
  __syncthreads();

  // Stockham radix-2 inverse FFT (unnormalized), 10 stages, self-sorting
  float2* src = bufA;
  float2* dst = bufB;
  for (int stage = 0; stage < 10; stage++) {
    int m = 1 << stage;
    for (int idx = tid; idx < 512; idx += 256) {
      int jm = idx & ~(m - 1);
      float2 a = src[idx];
      float2 bv = src[idx + 512];
      float2 sum = make_float2(a.x + bv.x, a.y + bv.y);
      float2 dif = make_float2(a.x - bv.x, a.y - bv.y);
      float2 w = T[2 * jm];
      float2 o1 = make_float2(w.x * dif.x - w.y * dif.y, w.x * dif.y + w.y * dif.x);
      dst[idx + jm] = sum;
      dst[idx + jm + m] = o1;
    }
    __syncthreads();
    float2* tmp = src; src = dst; dst = tmp;
  }
  // result in src; x[2m]=Re/2048, x[2m+1]=Im/2048; apply Hann, overwrite slot with frame
  float* slot_f = ws + (size_t)r * SLOT_DW;
  const float inv_n = 1.0f / 2048.0f;
  for (int i = tid; i < 2048; i += 256) {
    float2 zc = src[i >> 1];
    float v = (i & 1) ? zc.y : zc.x;
    float c = (i <= 1024) ? T[i].x : T[2048 - i].x;  // cos(pi*i/1024)
    float win = 0.5f * (1.0f - c);
    slot_f[i] = v * inv_n * win;
  }
}

// ---------------- KC: overlap-add gather + env normalize + crop ----------------
__global__ __launch_bounds__(256) void kC(const float* __restrict__ ws,
                                          float* __restrict__ out) {
  int b = blockIdx.y;
  int p = blockIdx.x * 256 + threadIdx.x;   // 0..1048063 (exact grid)
  int q = p + 1024;
  int t0 = (q - 1536) >> 9; if (t0 < 0) t0 = 0;
  int t1 = q >> 9;          if (t1 > 2047) t1 = 2047;
  float sum = 0.f, env = 0.f;
  for (int t = t0; t <= t1; t++) {
    int i = q - (t << 9);
    float c = cosf((float)i * 3.0679615757712823e-3f);  // cos(pi*i/1024)
    float win = 0.5f * (1.0f - c);
    sum += ws[(size_t)(b * 2048 + t) * SLOT_DW + i];    // frames already windowed
    env += win * win;
  }
  out[(size_t)b * 1048064 + p] = sum / (env > 1e-11f ? env : 1.0f);
}

extern "C" void kernel_launch(void* const* d_in, const int* in_sizes, int n_in,
                              void* d_out, int out_size, void* d_ws, size_t ws_size,
                              hipStream_t stream) {
  const float* z    = (const float*)d_in[0];
  const float* mix  = (const float*)d_in[1];
  const float* W    = (const float*)d_in[2];
  const float* bias = (const float*)d_in[3];
  float* out = (float*)d_out;
  _Float16* Wt = (_Float16*)((char*)d_ws + WT_BYTE_OFF);

  k_transpose<<<22, 256, 0, stream>>>(W, Wt);
  kA<<<dim3(256, 22), 256, 0, stream>>>(z, Wt, (_Float16*)d_ws);
  kB<<<16384, 256, 0, stream>>>(mix, bias, (float*)d_ws);
  kC<<<dim3(4094, 8), 256, 0, stream>>>((const float*)d_ws, out);
}

// Round 2
// 534.140 us; speedup vs baseline: 1.2935x; 1.2935x over previous
//
#include <hip/hip_runtime.h>

typedef _Float16 f16x8 __attribute__((ext_vector_type(8)));
typedef float f32x4 __attribute__((ext_vector_type(4)));

#define SLOT_DW 2048              // dwords per (b,t) slot: kA writes 1408 dw (f16 band), kB overwrites with 2048 dw frame
#define WT_BYTE_OFF 134217728     // 16384*2048*4 ; Wt (f16) after slots
#define T_BYTE_OFF  134938624     // WT_BYTE_OFF + 22*16384*2 ; twiddle table float2[1025]

// ---------------- K0: transpose+scale W -> Wt[n][o][d] (f16, x4096); block 22 fills twiddle table ----------------
__global__ __launch_bounds__(256) void k_init(const float* __restrict__ W,
                                              _Float16* __restrict__ Wt,
                                              float2* __restrict__ Tg) {
  int n = blockIdx.x;
  int tid = threadIdx.x;
  if (n == 22) {
    for (int k = tid; k < 1025; k += 256) {
      float sv, cv;
      sincosf((float)k * 3.0679615757712823e-3f, &sv, &cv);  // pi/1024
      Tg[k] = make_float2(cv, sv);
    }
    return;
  }
  __shared__ _Float16 L[128 * 130];
  const float* Wn = W + (size_t)n * 16384;
  for (int el = tid; el < 16384; el += 256) {
    int d = el >> 7, o = el & 127;
    L[d * 130 + o] = (_Float16)(Wn[el] * 4096.0f);
  }
  __syncthreads();
  _Float16* Wtn = Wt + (size_t)n * 16384;
  for (int el = tid; el < 16384; el += 256) {
    int o = el >> 7, d = el & 127;
    Wtn[el] = L[d * 130 + o];
  }
}

// ---------------- KA: per-band GEMM, band[r][n*128+o] = sum_d z[r][n][d]*W[n][d][o] ----------------
__global__ __launch_bounds__(256) void kA(const float* __restrict__ z,
                                          const _Float16* __restrict__ Wt,
                                          _Float16* __restrict__ band) {
  int mt = blockIdx.x;   // 0..255
  int n  = blockIdx.y;   // 0..21
  int r0 = mt * 64;
  __shared__ __align__(16) _Float16 As[64 * 136];
  __shared__ __align__(16) _Float16 Bs[128 * 136];
  int tid = threadIdx.x;
  int cg = tid & 15, rg = tid >> 4;

#pragma unroll
  for (int pass = 0; pass < 4; pass++) {
    int row = pass * 16 + rg;
    const float* src = z + ((size_t)(r0 + row) * 22 + n) * 128 + cg * 8;
    float4 v0 = *(const float4*)src;
    float4 v1 = *(const float4*)(src + 4);
    f16x8 h;
    h[0] = (_Float16)v0.x; h[1] = (_Float16)v0.y; h[2] = (_Float16)v0.z; h[3] = (_Float16)v0.w;
    h[4] = (_Float16)v1.x; h[5] = (_Float16)v1.y; h[6] = (_Float16)v1.z; h[7] = (_Float16)v1.w;
    *(f16x8*)&As[row * 136 + cg * 8] = h;
  }
  const _Float16* Wn = Wt + (size_t)n * 16384;
#pragma unroll
  for (int pass = 0; pass < 8; pass++) {
    int o = pass * 16 + rg;
    *(f16x8*)&Bs[o * 136 + cg * 8] = *(const f16x8*)(Wn + o * 128 + cg * 8);
  }
  __syncthreads();

  int lane = tid & 63, wave = tid >> 6;
  int l16 = lane & 15, quad = lane >> 4;
  f32x4 acc[8];
#pragma unroll
  for (int nt = 0; nt < 8; nt++) acc[nt] = (f32x4){0.f, 0.f, 0.f, 0.f};
#pragma unroll
  for (int kb = 0; kb < 4; kb++) {
    f16x8 a = *(const f16x8*)&As[(wave * 16 + l16) * 136 + kb * 32 + quad * 8];
#pragma unroll
    for (int nt = 0; nt < 8; nt++) {
      f16x8 bf = *(const f16x8*)&Bs[(nt * 16 + l16) * 136 + kb * 32 + quad * 8];
      acc[nt] = __builtin_amdgcn_mfma_f32_16x16x32_f16(a, bf, acc[nt], 0, 0, 0);
    }
  }
  __syncthreads();   // all MFMA LDS reads done; reuse As as output staging
  const float inv_scale = 1.0f / 4096.0f;
#pragma unroll
  for (int nt = 0; nt < 8; nt++) {
#pragma unroll
    for (int reg = 0; reg < 4; reg++) {
      int row = wave * 16 + quad * 4 + reg;
      As[row * 136 + nt * 16 + l16] = (_Float16)(acc[nt][reg] * inv_scale);
    }
  }
  __syncthreads();
  // coalesced store: 4 threads per row, 32 f16 (64B) each -> 256B contiguous per row
  int row = tid >> 2;
  int c4 = (tid & 3) * 32;
  const _Float16* srcl = &As[row * 136 + c4];
  _Float16* dst = band + (size_t)(r0 + row) * (SLOT_DW * 2) + n * 128 + c4;
  f16x8 v0 = *(const f16x8*)(srcl);
  f16x8 v1 = *(const f16x8*)(srcl + 8);
  f16x8 v2 = *(const f16x8*)(srcl + 16);
  f16x8 v3 = *(const f16x8*)(srcl + 24);
  *(f16x8*)(dst)      = v0;
  *(f16x8*)(dst + 8)  = v1;
  *(f16x8*)(dst + 16) = v2;
  *(f16x8*)(dst + 24) = v3;
}

// ---------------- KB: gather mask, complex-mul mix, irfft(2048), window, write frame in-place ----------------
__global__ __launch_bounds__(256, 6) void kB(const float* __restrict__ mix,
                                             const float* __restrict__ bias,
                                             float* __restrict__ ws) {
  int r = blockIdx.x;           // 0..16383
  int b = r >> 11, t = r & 2047;
  __shared__ __align__(16) unsigned char smem[24592];
  float2* Tl   = (float2*)smem;                    // [0,8200)  : 1025 twiddles
  float2* bufA = (float2*)(smem + 8200);           // [8200,16392)
  float*  sr   = (float*)(smem + 16392);           // [16392,20492)
  float*  si   = (float*)(smem + 20492);           // [20492,24592)
  float2* bufB = (float2*)(smem + 16392);          // aliases sr/si (dead after pack)
  int tid = threadIdx.x;

  const float2* Tg = (const float2*)((const char*)ws + (T_BYTE_OFF - 0) + 0);
  {
    const float2* Tgg = (const float2*)((const char*)ws + T_BYTE_OFF);
    for (int i = tid; i < 1025; i += 256) Tl[i] = Tgg[i];
  }
  (void)Tg;

  const _Float16* bandg = (const _Float16*)(ws + (size_t)r * SLOT_DW);
  const float* mixr = mix + ((size_t)(b * 2) * 2048 + t) * 1025;
  const float* mixi = mix + ((size_t)(b * 2 + 1) * 2048 + t) * 1025;
  for (int f = tid; f < 1025; f += 256) {
    float mr = 0.f, mi = 0.f;
    int wgt = 0;
    int nhi = f / 48; if (nhi > 20) nhi = 20;
    int nlo = (f >= 16) ? (f - 16) / 48 : 0;
    for (int n = nlo; n <= nhi; n++) {
      int idx = n * 128 + 2 * (f - n * 48);
      mr += (float)bandg[idx]     + bias[idx];
      mi += (float)bandg[idx + 1] + bias[idx + 1];
      wgt++;
    }
    if (f >= 961) {
      int idx = 21 * 128 + 2 * (f - 961);
      mr += (float)bandg[idx]     + bias[idx];
      mi += (float)bandg[idx + 1] + bias[idx + 1];
      wgt++;
    }
    float inv = (wgt == 1) ? 1.0f : ((wgt == 2) ? 0.5f : (1.0f / 3.0f));
    mr *= inv; mi *= inv;
    float xr = mixr[f], xi = mixi[f];
    float outr = mr * xr - mi * xi;
    float outi = mr * xi + mi * xr;
    if (f == 0 || f == 1024) outi = 0.0f;  // c2r ignores Im at DC/Nyquist
    sr[f] = outr; si[f] = outi;
  }
  __syncthreads();

  // pack real-IFFT(2048) into complex IFFT(1024)
  for (int k = tid; k < 1024; k += 256) {
    float Xr = sr[k], Xi = si[k];
    float Yr = sr[1024 - k], Yi = -si[1024 - k];
    float Ar = Xr + Yr, Ai = Xi + Yi;
    float Br = Xr - Yr, Bi = Xi - Yi;
    float2 w = Tl[k];
    bufA[k] = make_float2(Ar - (w.x * Bi + w.y * Br), Ai + (w.x * Br - w.y * Bi));
  }
  __syncthreads();

  // Stockham radix-2 inverse FFT (unnormalized), 10 stages
  float2* src = bufA;
  float2* dst = bufB;
  for (int stage = 0; stage < 10; stage++) {
    int m = 1 << stage;
    for (int idx = tid; idx < 512; idx += 256) {
      int jm = idx & ~(m - 1);
      float2 a = src[idx];
      float2 bv = src[idx + 512];
      float2 sum = make_float2(a.x + bv.x, a.y + bv.y);
      float2 dif = make_float2(a.x - bv.x, a.y - bv.y);
      float2 w = Tl[2 * jm];
      float2 o1 = make_float2(w.x * dif.x - w.y * dif.y, w.x * dif.y + w.y * dif.x);
      dst[idx + jm] = sum;
      dst[idx + jm + m] = o1;
    }
    __syncthreads();
    float2* tmp = src; src = dst; dst = tmp;
  }
  // result in src (=bufA after 10 swaps); apply Hann, overwrite slot with windowed frame
  float* slot_f = ws + (size_t)r * SLOT_DW;
  const float inv_n = 1.0f / 2048.0f;
  for (int i = tid; i < 2048; i += 256) {
    float2 zc = src[i >> 1];
    float v = (i & 1) ? zc.y : zc.x;
    float c = (i <= 1024) ? Tl[i].x : Tl[2048 - i].x;  // cos(pi*i/1024)
    float win = 0.5f * (1.0f - c);
    slot_f[i] = v * inv_n * win;
  }
}

// ---------------- KC: overlap-add gather + env normalize + crop ----------------
__global__ __launch_bounds__(256) void kC(const float* __restrict__ ws,
                                          float* __restrict__ out) {
  int b = blockIdx.y;
  int p = blockIdx.x * 256 + threadIdx.x;   // 0..1048063 (exact grid)
  int q = p + 1024;
  int t0 = (q - 1536) >> 9; if (t0 < 0) t0 = 0;
  int t1 = q >> 9;          if (t1 > 2047) t1 = 2047;
  float sum = 0.f;
  for (int t = t0; t <= t1; t++) {
    int i = q - (t << 9);
    sum += ws[(size_t)(b * 2048 + t) * SLOT_DW + i];    // frames already windowed
  }
  float env;
  if (t1 - t0 == 3) {
    env = 1.5f;  // Hann, hop=WIN/4: sum of win^2 over 4 phases is exactly 1.5
  } else {
    env = 0.f;
    for (int t = t0; t <= t1; t++) {
      int i = q - (t << 9);
      float c = cosf((float)i * 3.0679615757712823e-3f);  // cos(pi*i/1024)
      float win = 0.5f * (1.0f - c);
      env += win * win;
    }
  }
  out[(size_t)b * 1048064 + p] = sum / (env > 1e-11f ? env : 1.0f);
}

extern "C" void kernel_launch(void* const* d_in, const int* in_sizes, int n_in,
                              void* d_out, int out_size, void* d_ws, size_t ws_size,
                              hipStream_t stream) {
  const float* z    = (const float*)d_in[0];
  const float* mix  = (const float*)d_in[1];
  const float* W    = (const float*)d_in[2];
  const float* bias = (const float*)d_in[3];
  float* out = (float*)d_out;
  _Float16* Wt = (_Float16*)((char*)d_ws + WT_BYTE_OFF);
  float2* Tg = (float2*)((char*)d_ws + T_BYTE_OFF);

  k_init<<<23, 256, 0, stream>>>(W, Wt, Tg);
  kA<<<dim3(256, 22), 256, 0, stream>>>(z, Wt, (_Float16*)d_ws);
  kB<<<16384, 256, 0, stream>>>(mix, bias, (float*)d_ws);
  kC<<<dim3(4094, 8), 256, 0, stream>>>((const float*)d_ws, out);
}

// Round 3
// 532.403 us; speedup vs baseline: 1.2977x; 1.0033x over previous
//
#include <hip/hip_runtime.h>

typedef _Float16 f16x8 __attribute__((ext_vector_type(8)));
typedef _Float16 f16x2 __attribute__((ext_vector_type(2)));
typedef float f32x4 __attribute__((ext_vector_type(4)));

#define SLOT_DW 2048              // dwords per (b,t) slot: kA writes 1408 dw (f16 band), kB overwrites with 2048 dw frame
#define WT_BYTE_OFF 134217728     // 16384*2048*4 ; Wt (f16) after slots
#define PHYS(i) ((i) + ((i) >> 5))   // LDS pad swizzle for FFT buffers

// ---------------- K0: transpose+scale W -> Wt[n][o][d] (f16, x4096) ----------------
__global__ __launch_bounds__(256) void k_init(const float* __restrict__ W,
                                              _Float16* __restrict__ Wt) {
  int n = blockIdx.x;
  int tid = threadIdx.x;
  __shared__ _Float16 L[128 * 130];
  const float* Wn = W + (size_t)n * 16384;
  for (int el = tid; el < 16384; el += 256) {
    int d = el >> 7, o = el & 127;
    L[d * 130 + o] = (_Float16)(Wn[el] * 4096.0f);
  }
  __syncthreads();
  _Float16* Wtn = Wt + (size_t)n * 16384;
  for (int el = tid; el < 16384; el += 256) {
    int o = el >> 7, d = el & 127;
    Wtn[el] = L[d * 130 + o];
  }
}

// ---------------- KA: per-band GEMM, no LDS staging in main loop ----------------
// block: 64 rows x 128 cols, one band. Wave w owns col-tiles {2w, 2w+1} over all 4 row-tiles.
__global__ __launch_bounds__(256) void kA(const float* __restrict__ z,
                                          const _Float16* __restrict__ Wt,
                                          _Float16* __restrict__ band) {
  int mt = blockIdx.x;   // 0..255
  int n  = blockIdx.y;   // 0..21
  int r0 = mt * 64;
  __shared__ __align__(16) _Float16 Cs[64 * 136];
  int tid = threadIdx.x;
  int lane = tid & 63, wave = tid >> 6;
  int l16 = lane & 15, quad = lane >> 4;

  const _Float16* Wn = Wt + (size_t)n * 16384;
  f32x4 acc[2][4];
#pragma unroll
  for (int c = 0; c < 2; c++)
#pragma unroll
    for (int rt = 0; rt < 4; rt++) acc[c][rt] = (f32x4){0.f, 0.f, 0.f, 0.f};

#pragma unroll
  for (int kb = 0; kb < 4; kb++) {
    int ko = kb * 32 + quad * 8;
    f16x8 b0 = *(const f16x8*)(Wn + (wave * 32 + l16) * 128 + ko);
    f16x8 b1 = *(const f16x8*)(Wn + (wave * 32 + 16 + l16) * 128 + ko);
#pragma unroll
    for (int rt = 0; rt < 4; rt++) {
      const float* src = z + ((size_t)(r0 + rt * 16 + l16) * 22 + n) * 128 + ko;
      float4 v0 = *(const float4*)src;
      float4 v1 = *(const float4*)(src + 4);
      f16x8 a;
      a[0] = (_Float16)v0.x; a[1] = (_Float16)v0.y; a[2] = (_Float16)v0.z; a[3] = (_Float16)v0.w;
      a[4] = (_Float16)v1.x; a[5] = (_Float16)v1.y; a[6] = (_Float16)v1.z; a[7] = (_Float16)v1.w;
      acc[0][rt] = __builtin_amdgcn_mfma_f32_16x16x32_f16(a, b0, acc[0][rt], 0, 0, 0);
      acc[1][rt] = __builtin_amdgcn_mfma_f32_16x16x32_f16(a, b1, acc[1][rt], 0, 0, 0);
    }
  }
  const float inv_scale = 1.0f / 4096.0f;
#pragma unroll
  for (int c = 0; c < 2; c++) {
    int col = (wave * 2 + c) * 16 + l16;
#pragma unroll
    for (int rt = 0; rt < 4; rt++) {
#pragma unroll
      for (int reg = 0; reg < 4; reg++) {
        int row = rt * 16 + quad * 4 + reg;
        Cs[row * 136 + col] = (_Float16)(acc[c][rt][reg] * inv_scale);
      }
    }
  }
  __syncthreads();
  int row = tid >> 2;
  int c4 = (tid & 3) * 32;
  const _Float16* srcl = &Cs[row * 136 + c4];
  _Float16* dst = band + (size_t)(r0 + row) * (SLOT_DW * 2) + n * 128 + c4;
  f16x8 v0 = *(const f16x8*)(srcl);
  f16x8 v1 = *(const f16x8*)(srcl + 8);
  f16x8 v2 = *(const f16x8*)(srcl + 16);
  f16x8 v3 = *(const f16x8*)(srcl + 24);
  *(f16x8*)(dst)      = v0;
  *(f16x8*)(dst + 8)  = v1;
  *(f16x8*)(dst + 16) = v2;
  *(f16x8*)(dst + 24) = v3;
}

// ---------------- KB: mask gather + pack (conjugate pairs) + radix-4 Stockham IFFT + window ----------------
__global__ __launch_bounds__(256) void kB(const float* __restrict__ mix,
                                          const float* __restrict__ bias,
                                          float* __restrict__ ws) {
  int r = blockIdx.x;           // 0..16383
  int b = r >> 11, t = r & 2047;
  __shared__ __align__(16) float2 bufA[1056];   // swizzled: PHYS(i)=i+(i>>5)
  __shared__ __align__(16) float2 bufB[1056];
  int tid = threadIdx.x;

  const _Float16* bandg = (const _Float16*)(ws + (size_t)r * SLOT_DW);
  const float2* bias2 = (const float2*)bias;
  const float* mixr = mix + ((size_t)(b * 2) * 2048 + t) * 1025;
  const float* mixi = mix + ((size_t)(b * 2 + 1) * 2048 + t) * 1025;

  // ---- fused mask gather + complex-mul + real-pack (pairs k, 1024-k) ----
  for (int k = tid; k <= 512; k += 256) {
    float2 X[2];
#pragma unroll
    for (int side = 0; side < 2; side++) {
      int f = side ? (1024 - k) : k;
      float mr = 0.f, mi = 0.f;
      int wgt = 0;
      int nhi = f / 48; if (nhi > 20) nhi = 20;
      int nlo = (f >= 16) ? (f - 16) / 48 : 0;
      for (int n = nlo; n <= nhi; n++) {
        int idx = n * 128 + 2 * (f - n * 48);
        f16x2 bv = *(const f16x2*)(bandg + idx);
        float2 bb = bias2[idx >> 1];
        mr += (float)bv[0] + bb.x;
        mi += (float)bv[1] + bb.y;
        wgt++;
      }
      if (f >= 961) {
        int idx = 21 * 128 + 2 * (f - 961);
        f16x2 bv = *(const f16x2*)(bandg + idx);
        float2 bb = bias2[idx >> 1];
        mr += (float)bv[0] + bb.x;
        mi += (float)bv[1] + bb.y;
        wgt++;
      }
      float inv = (wgt == 1) ? 1.0f : ((wgt == 2) ? 0.5f : (1.0f / 3.0f));
      mr *= inv; mi *= inv;
      float xr = mixr[f], xi = mixi[f];
      float outr = mr * xr - mi * xi;
      float outi = mr * xi + mi * xr;
      if (f == 0 || f == 1024) outi = 0.0f;   // c2r ignores Im at DC/Nyquist
      X[side] = make_float2(outr, outi);
      if (k == 512) { X[1] = X[0]; break; }   // self-paired center
    }
    // Y = conj(X[1024-k]); A = X + Y; B = X - Y; w = e^{i pi k/1024}
    float Ar = X[0].x + X[1].x, Ai = X[0].y - X[1].y;
    float Br = X[0].x - X[1].x, Bi = X[0].y + X[1].y;
    float sv, cv;
    __sincosf((float)k * 3.0679615757712823e-3f, &sv, &cv);   // pi/1024
    float s1 = cv * Bi + sv * Br;
    float s2 = cv * Br - sv * Bi;
    bufA[PHYS(k & 1023)] = make_float2(Ar - s1, Ai + s2);     // G[k] (k=1024 impossible here)
    if (k > 0 && k < 512) bufA[PHYS(1024 - k)] = make_float2(Ar + s1, -Ai + s2);  // G[1024-k]
  }

  // ---- radix-4 Stockham inverse FFT (5 double-stages, e^{+i} twiddles, unnormalized) ----
  float2* src = bufA;
  float2* dst = bufB;
#pragma unroll
  for (int st = 0; st < 5; st++) {
    const int s = 2 * st;
    const int m = 1 << s;
    __syncthreads();
    int q = tid >> s, rr = tid & (m - 1);
    float2 x0 = src[PHYS(tid)];
    float2 x1 = src[PHYS(tid + 256)];
    float2 x2 = src[PHYS(tid + 512)];
    float2 x3 = src[PHYS(tid + 768)];
    float ang = (float)(q * m) * 6.135923151542565e-3f;   // 2*pi*q*m/1024
    float ws1, wc1;
    __sincosf(ang, &ws1, &wc1);
    float wc2 = wc1 * wc1 - ws1 * ws1, ws2 = 2.0f * wc1 * ws1;
    float wc3 = wc2 * wc1 - ws2 * ws1, ws3 = wc2 * ws1 + ws2 * wc1;
    float tAr = x0.x + x2.x, tAi = x0.y + x2.y;
    float tBr = x0.x - x2.x, tBi = x0.y - x2.y;
    float tCr = x1.x + x3.x, tCi = x1.y + x3.y;
    float tDr = x1.x - x3.x, tDi = x1.y - x3.y;
    int base = 4 * q * m + rr;
    dst[PHYS(base)] = make_float2(tAr + tCr, tAi + tCi);
    float pr = tBr - tDi, pi = tBi + tDr;                  // tB + i*tD
    dst[PHYS(base + m)] = make_float2(wc1 * pr - ws1 * pi, wc1 * pi + ws1 * pr);
    float qr = tAr - tCr, qi = tAi - tCi;
    dst[PHYS(base + 2 * m)] = make_float2(wc2 * qr - ws2 * qi, wc2 * qi + ws2 * qr);
    float rr2 = tBr + tDi, ri2 = tBi - tDr;                // tB - i*tD
    dst[PHYS(base + 3 * m)] = make_float2(wc3 * rr2 - ws3 * ri2, wc3 * ri2 + ws3 * rr2);
    float2* tmp = src; src = dst; dst = tmp;
  }
  __syncthreads();

  // ---- window + store frame (x[2j]=Re(g[j])/2048, x[2j+1]=Im(g[j])/2048) ----
  float2* slot2 = (float2*)(ws + (size_t)r * SLOT_DW);
  const float inv_n = 1.0f / 2048.0f;
  for (int j = tid; j < 1024; j += 256) {
    float2 g = src[PHYS(j)];
    float c0 = __cosf((float)(2 * j) * 3.0679615757712823e-3f);       // cos(pi*2j/1024)
    float c1 = __cosf((float)(2 * j + 1) * 3.0679615757712823e-3f);
    float w0 = 0.5f * (1.0f - c0);
    float w1 = 0.5f * (1.0f - c1);
    slot2[j] = make_float2(g.x * inv_n * w0, g.y * inv_n * w1);
  }
}

// ---------------- KC: overlap-add gather + env normalize + crop ----------------
__global__ __launch_bounds__(256) void kC(const float* __restrict__ ws,
                                          float* __restrict__ out) {
  int b = blockIdx.y;
  int p = blockIdx.x * 256 + threadIdx.x;   // 0..1048063 (exact grid)
  int q = p + 1024;
  int t0 = (q - 1536) >> 9; if (t0 < 0) t0 = 0;
  int t1 = q >> 9;          if (t1 > 2047) t1 = 2047;
  float sum = 0.f;
  for (int t = t0; t <= t1; t++) {
    int i = q - (t << 9);
    sum += ws[(size_t)(b * 2048 + t) * SLOT_DW + i];    // frames already windowed
  }
  float env;
  if (t1 - t0 == 3) {
    env = 1.5f;  // Hann, hop=WIN/4: interior sum of win^2 is exactly 1.5
  } else {
    env = 0.f;
    for (int t = t0; t <= t1; t++) {
      int i = q - (t << 9);
      float c = __cosf((float)i * 3.0679615757712823e-3f);
      float win = 0.5f * (1.0f - c);
      env += win * win;
    }
  }
  out[(size_t)b * 1048064 + p] = sum / (env > 1e-11f ? env : 1.0f);
}

extern "C" void kernel_launch(void* const* d_in, const int* in_sizes, int n_in,
                              void* d_out, int out_size, void* d_ws, size_t ws_size,
                              hipStream_t stream) {
  const float* z    = (const float*)d_in[0];
  const float* mix  = (const float*)d_in[1];
  const float* W    = (const float*)d_in[2];
  const float* bias = (const float*)d_in[3];
  float* out = (float*)d_out;
  _Float16* Wt = (_Float16*)((char*)d_ws + WT_BYTE_OFF);

  k_init<<<22, 256, 0, stream>>>(W, Wt);
  kA<<<dim3(256, 22), 256, 0, stream>>>(z, Wt, (_Float16*)d_ws);
  kB<<<16384, 256, 0, stream>>>(mix, bias, (float*)d_ws);
  kC<<<dim3(4094, 8), 256, 0, stream>>>((const float*)d_ws, out);
}

// Round 4
// 487.684 us; speedup vs baseline: 1.4167x; 1.0917x over previous
//
#include <hip/hip_runtime.h>

typedef _Float16 f16x8 __attribute__((ext_vector_type(8)));
typedef _Float16 f16x2 __attribute__((ext_vector_type(2)));
typedef float f32x4 __attribute__((ext_vector_type(4)));

#define SLOT_DW 2048              // dwords per (b,t) slot: kA writes 1408 dw (f16 band), kB overwrites with 2048 dw frame
#define WT_BYTE_OFF 134217728     // 16384*2048*4 ; Wt (f16) after slots
#define PHYS(i) ((i) + ((i) >> 5))   // LDS pad swizzle for FFT buffers

__device__ __forceinline__ void async_copy16(const void* g, void* l) {
  __builtin_amdgcn_global_load_lds((const __attribute__((address_space(1))) void*)g,
                                   (__attribute__((address_space(3))) void*)l, 16, 0, 0);
}

// ---------------- K0: transpose+scale W -> Wt[n][o][d] (f16, x4096) ----------------
// 88 blocks: band n = bx>>2, d-quarter dq = bx&3 (32 d-rows each)
__global__ __launch_bounds__(256) void k_init(const float* __restrict__ W,
                                              _Float16* __restrict__ Wt) {
  int n = blockIdx.x >> 2, dq = blockIdx.x & 3;
  int tid = threadIdx.x;
  __shared__ _Float16 L[32 * 130];
  const float* Wn = W + (size_t)n * 16384 + dq * 32 * 128;
  for (int el = tid; el < 4096; el += 256) {
    int dl = el >> 7, o = el & 127;
    L[dl * 130 + o] = (_Float16)(Wn[el] * 4096.0f);
  }
  __syncthreads();
  _Float16* Wtn = Wt + (size_t)n * 16384 + dq * 32;
  for (int el = tid; el < 4096; el += 256) {
    int o = el >> 5, dl = el & 31;
    Wtn[o * 128 + dl] = L[dl * 130 + o];
  }
}

// ---------------- KA: per-band GEMM, async LDS staging + reg-resident B ----------------
// block: 64 rows x 128 cols, one band. Wave w owns col-tiles {2w,2w+1} over 4 row-tiles.
__global__ __launch_bounds__(256) void kA(const float* __restrict__ z,
                                          const _Float16* __restrict__ Wt,
                                          _Float16* __restrict__ band) {
  int mt = blockIdx.x;   // 0..255
  int n  = blockIdx.y;   // 0..21
  int r0 = mt * 64;
  __shared__ __align__(16) char smem[33280];   // 32 row-pairs x 1040B (fp32 z), aliased by epilogue Cs
  int tid = threadIdx.x;
  int lane = tid & 63, wave = tid >> 6;
  int l16 = lane & 15, quad = lane >> 4;

  // preload all B fragments (band-n weights; L2-hot across 256 blocks) -> 32 VGPRs
  const _Float16* Wn = Wt + (size_t)n * 16384;
  f16x8 bfrag[8];
#pragma unroll
  for (int kb = 0; kb < 4; kb++) {
    int ko = kb * 32 + quad * 8;
    bfrag[2 * kb]     = *(const f16x8*)(Wn + (wave * 32 + l16) * 128 + ko);
    bfrag[2 * kb + 1] = *(const f16x8*)(Wn + (wave * 32 + 16 + l16) * 128 + ko);
  }

  // async-stage 64 z rows (band n, fp32). Pair p -> LDS [p*1040, p*1040+1024).
  // One issue per wave: lanes 0-31 = row 2p (16B chunks), lanes 32-63 = row 2p+1.
  {
    int col16 = lane & 31;
    int rowh  = lane >> 5;
#pragma unroll
    for (int it = 0; it < 8; it++) {
      int pr = wave * 8 + it;
      const float* g = z + ((size_t)(r0 + 2 * pr + rowh) * 22 + n) * 128 + col16 * 4;
      async_copy16(g, smem + pr * 1040);
    }
  }
  __syncthreads();

  f32x4 acc[2][4];
#pragma unroll
  for (int c = 0; c < 2; c++)
#pragma unroll
    for (int rt = 0; rt < 4; rt++) acc[c][rt] = (f32x4){0.f, 0.f, 0.f, 0.f};

#pragma unroll
  for (int kb = 0; kb < 4; kb++) {
#pragma unroll
    for (int rt = 0; rt < 4; rt++) {
      int row = rt * 16 + l16;
      const float* ap = (const float*)(smem + (row >> 1) * 1040 + (row & 1) * 512) + kb * 32 + quad * 8;
      float4 v0 = *(const float4*)ap;
      float4 v1 = *(const float4*)(ap + 4);
      f16x8 a;
      a[0] = (_Float16)v0.x; a[1] = (_Float16)v0.y; a[2] = (_Float16)v0.z; a[3] = (_Float16)v0.w;
      a[4] = (_Float16)v1.x; a[5] = (_Float16)v1.y; a[6] = (_Float16)v1.z; a[7] = (_Float16)v1.w;
      acc[0][rt] = __builtin_amdgcn_mfma_f32_16x16x32_f16(a, bfrag[2 * kb],     acc[0][rt], 0, 0, 0);
      acc[1][rt] = __builtin_amdgcn_mfma_f32_16x16x32_f16(a, bfrag[2 * kb + 1], acc[1][rt], 0, 0, 0);
    }
  }
  __syncthreads();   // zs dead; reuse smem as Cs staging

  _Float16* Cs = (_Float16*)smem;
  const float inv_scale = 1.0f / 4096.0f;
#pragma unroll
  for (int c = 0; c < 2; c++) {
    int col = (wave * 2 + c) * 16 + l16;
#pragma unroll
    for (int rt = 0; rt < 4; rt++) {
#pragma unroll
      for (int reg = 0; reg < 4; reg++) {
        int row = rt * 16 + quad * 4 + reg;
        Cs[row * 136 + col] = (_Float16)(acc[c][rt][reg] * inv_scale);
      }
    }
  }
  __syncthreads();
  int row = tid >> 2;
  int c4 = (tid & 3) * 32;
  const _Float16* srcl = &Cs[row * 136 + c4];
  _Float16* dst = band + (size_t)(r0 + row) * (SLOT_DW * 2) + n * 128 + c4;
  f16x8 v0 = *(const f16x8*)(srcl);
  f16x8 v1 = *(const f16x8*)(srcl + 8);
  f16x8 v2 = *(const f16x8*)(srcl + 16);
  f16x8 v3 = *(const f16x8*)(srcl + 24);
  *(f16x8*)(dst)      = v0;
  *(f16x8*)(dst + 8)  = v1;
  *(f16x8*)(dst + 16) = v2;
  *(f16x8*)(dst + 24) = v3;
}

// ---------------- KB: mask gather + pack (conjugate pairs) + radix-4 Stockham IFFT + window ----------------
__global__ __launch_bounds__(256) void kB(const float* __restrict__ mix,
                                          const float* __restrict__ bias,
                                          float* __restrict__ ws) {
  int r = blockIdx.x;           // 0..16383
  int b = r >> 11, t = r & 2047;
  __shared__ __align__(16) float2 bufA[1056];   // swizzled: PHYS(i)=i+(i>>5)
  __shared__ __align__(16) float2 bufB[1056];
  int tid = threadIdx.x;

  const _Float16* bandg = (const _Float16*)(ws + (size_t)r * SLOT_DW);
  const float2* bias2 = (const float2*)bias;
  const float* mixr = mix + ((size_t)(b * 2) * 2048 + t) * 1025;
  const float* mixi = mix + ((size_t)(b * 2 + 1) * 2048 + t) * 1025;

  // ---- fused mask gather + complex-mul + real-pack (pairs k, 1024-k) ----
  for (int k = tid; k <= 512; k += 256) {
    float2 X[2];
#pragma unroll
    for (int side = 0; side < 2; side++) {
      int f = side ? (1024 - k) : k;
      float mr = 0.f, mi = 0.f;
      int wgt = 0;
      int nhi = f / 48; if (nhi > 20) nhi = 20;
      int nlo = (f >= 16) ? (f - 16) / 48 : 0;
      for (int n = nlo; n <= nhi; n++) {
        int idx = n * 128 + 2 * (f - n * 48);
        f16x2 bv = *(const f16x2*)(bandg + idx);
        float2 bb = bias2[idx >> 1];
        mr += (float)bv[0] + bb.x;
        mi += (float)bv[1] + bb.y;
        wgt++;
      }
      if (f >= 961) {
        int idx = 21 * 128 + 2 * (f - 961);
        f16x2 bv = *(const f16x2*)(bandg + idx);
        float2 bb = bias2[idx >> 1];
        mr += (float)bv[0] + bb.x;
        mi += (float)bv[1] + bb.y;
        wgt++;
      }
      float inv = (wgt == 1) ? 1.0f : ((wgt == 2) ? 0.5f : (1.0f / 3.0f));
      mr *= inv; mi *= inv;
      float xr = mixr[f], xi = mixi[f];
      float outr = mr * xr - mi * xi;
      float outi = mr * xi + mi * xr;
      if (f == 0 || f == 1024) outi = 0.0f;   // c2r ignores Im at DC/Nyquist
      X[side] = make_float2(outr, outi);
      if (k == 512) { X[1] = X[0]; break; }   // self-paired center
    }
    float Ar = X[0].x + X[1].x, Ai = X[0].y - X[1].y;
    float Br = X[0].x - X[1].x, Bi = X[0].y + X[1].y;
    float sv, cv;
    __sincosf((float)k * 3.0679615757712823e-3f, &sv, &cv);   // pi/1024
    float s1 = cv * Bi + sv * Br;
    float s2 = cv * Br - sv * Bi;
    bufA[PHYS(k & 1023)] = make_float2(Ar - s1, Ai + s2);
    if (k > 0 && k < 512) bufA[PHYS(1024 - k)] = make_float2(Ar + s1, -Ai + s2);
  }

  // ---- radix-4 Stockham inverse FFT (5 double-stages, e^{+i} twiddles, unnormalized) ----
  float2* src = bufA;
  float2* dst = bufB;
#pragma unroll
  for (int st = 0; st < 5; st++) {
    const int s = 2 * st;
    const int m = 1 << s;
    __syncthreads();
    int q = tid >> s, rr = tid & (m - 1);
    float2 x0 = src[PHYS(tid)];
    float2 x1 = src[PHYS(tid + 256)];
    float2 x2 = src[PHYS(tid + 512)];
    float2 x3 = src[PHYS(tid + 768)];
    float ang = (float)(q * m) * 6.135923151542565e-3f;   // 2*pi*q*m/1024
    float ws1, wc1;
    __sincosf(ang, &ws1, &wc1);
    float wc2 = wc1 * wc1 - ws1 * ws1, ws2 = 2.0f * wc1 * ws1;
    float wc3 = wc2 * wc1 - ws2 * ws1, ws3 = wc2 * ws1 + ws2 * wc1;
    float tAr = x0.x + x2.x, tAi = x0.y + x2.y;
    float tBr = x0.x - x2.x, tBi = x0.y - x2.y;
    float tCr = x1.x + x3.x, tCi = x1.y + x3.y;
    float tDr = x1.x - x3.x, tDi = x1.y - x3.y;
    int base = 4 * q * m + rr;
    dst[PHYS(base)] = make_float2(tAr + tCr, tAi + tCi);
    float pr = tBr - tDi, pi = tBi + tDr;                  // tB + i*tD
    dst[PHYS(base + m)] = make_float2(wc1 * pr - ws1 * pi, wc1 * pi + ws1 * pr);
    float qr = tAr - tCr, qi = tAi - tCi;
    dst[PHYS(base + 2 * m)] = make_float2(wc2 * qr - ws2 * qi, wc2 * qi + ws2 * qr);
    float rr2 = tBr + tDi, ri2 = tBi - tDr;                // tB - i*tD
    dst[PHYS(base + 3 * m)] = make_float2(wc3 * rr2 - ws3 * ri2, wc3 * ri2 + ws3 * rr2);
    float2* tmp = src; src = dst; dst = tmp;
  }
  __syncthreads();

  // ---- window + store frame (x[2j]=Re(g[j])/2048, x[2j+1]=Im(g[j])/2048) ----
  float2* slot2 = (float2*)(ws + (size_t)r * SLOT_DW);
  const float inv_n = 1.0f / 2048.0f;
  for (int j = tid; j < 1024; j += 256) {
    float2 g = src[PHYS(j)];
    float c0 = __cosf((float)(2 * j) * 3.0679615757712823e-3f);
    float c1 = __cosf((float)(2 * j + 1) * 3.0679615757712823e-3f);
    float w0 = 0.5f * (1.0f - c0);
    float w1 = 0.5f * (1.0f - c1);
    slot2[j] = make_float2(g.x * inv_n * w0, g.y * inv_n * w1);
  }
}

// ---------------- KC: overlap-add gather + env normalize + crop ----------------
__global__ __launch_bounds__(256) void kC(const float* __restrict__ ws,
                                          float* __restrict__ out) {
  int b = blockIdx.y;
  int p = blockIdx.x * 256 + threadIdx.x;   // 0..1048063 (exact grid)
  int q = p + 1024;
  int t0 = (q - 1536) >> 9; if (t0 < 0) t0 = 0;
  int t1 = q >> 9;          if (t1 > 2047) t1 = 2047;
  float sum = 0.f;
  for (int t = t0; t <= t1; t++) {
    int i = q - (t << 9);
    sum += ws[(size_t)(b * 2048 + t) * SLOT_DW + i];    // frames already windowed
  }
  float env;
  if (t1 - t0 == 3) {
    env = 1.5f;  // Hann, hop=WIN/4: interior sum of win^2 is exactly 1.5
  } else {
    env = 0.f;
    for (int t = t0; t <= t1; t++) {
      int i = q - (t << 9);
      float c = __cosf((float)i * 3.0679615757712823e-3f);
      float win = 0.5f * (1.0f - c);
      env += win * win;
    }
  }
  out[(size_t)b * 1048064 + p] = sum / (env > 1e-11f ? env : 1.0f);
}

extern "C" void kernel_launch(void* const* d_in, const int* in_sizes, int n_in,
                              void* d_out, int out_size, void* d_ws, size_t ws_size,
                              hipStream_t stream) {
  const float* z    = (const float*)d_in[0];
  const float* mix  = (const float*)d_in[1];
  const float* W    = (const float*)d_in[2];
  const float* bias = (const float*)d_in[3];
  float* out = (float*)d_out;
  _Float16* Wt = (_Float16*)((char*)d_ws + WT_BYTE_OFF);

  k_init<<<88, 256, 0, stream>>>(W, Wt);
  kA<<<dim3(256, 22), 256, 0, stream>>>(z, Wt, (_Float16*)d_ws);
  kB<<<16384, 256, 0, stream>>>(mix, bias, (float*)d_ws);
  kC<<<dim3(4094, 8), 256, 0, stream>>>((const float*)d_ws, out);
}